// Round 16
// baseline (129.196 us; speedup 1.0000x reference)
//
#include <hip/hip_runtime.h>
#include <hip/hip_bf16.h>

namespace {

typedef unsigned short u16;
typedef unsigned int u32;
typedef unsigned char u8;
typedef __attribute__((ext_vector_type(8))) short bf16x8;
typedef __attribute__((ext_vector_type(4))) float f32x4;
typedef __attribute__((ext_vector_type(2))) float f32x2;

constexpr int kNQ   = 10000;
constexpr int kCams = 6;
constexpr int kC    = 256;
constexpr int kNK   = 13600;
constexpr float kEps = 1e-5f;

__device__ __forceinline__ u16 f2b(float f) {
  union { __hip_bfloat16 h; u16 u; } cv;
  cv.h = __float2bfloat16(f);   // hardware cvt, RNE
  return cv.u;
}
__device__ __forceinline__ float b2f(u16 b) {
  return __uint_as_float(((u32)b) << 16);
}
__device__ __forceinline__ bf16x8 pack8(const float4& a, const float4& b) {
  bf16x8 v;
  v[0] = (short)f2b(a.x); v[1] = (short)f2b(a.y);
  v[2] = (short)f2b(a.z); v[3] = (short)f2b(a.w);
  v[4] = (short)f2b(b.x); v[5] = (short)f2b(b.y);
  v[6] = (short)f2b(b.z); v[7] = (short)f2b(b.w);
  return v;
}
__device__ __forceinline__ bf16x8 cvt8(const f32x4 lo, const f32x4 hi) {
  bf16x8 v;
  v[0] = (short)f2b(lo[0]); v[1] = (short)f2b(lo[1]);
  v[2] = (short)f2b(lo[2]); v[3] = (short)f2b(lo[3]);
  v[4] = (short)f2b(hi[0]); v[5] = (short)f2b(hi[1]);
  v[6] = (short)f2b(hi[2]); v[7] = (short)f2b(hi[3]);
  return v;
}
__device__ __forceinline__ bf16x8 load8sum(const float* a, const float* b) {
  const float4 a0 = *reinterpret_cast<const float4*>(a);
  const float4 a1 = *reinterpret_cast<const float4*>(a + 4);
  const float4 b0 = *reinterpret_cast<const float4*>(b);
  const float4 b1 = *reinterpret_cast<const float4*>(b + 4);
  float4 s0, s1;
  s0.x = a0.x + b0.x; s0.y = a0.y + b0.y; s0.z = a0.z + b0.z; s0.w = a0.w + b0.w;
  s1.x = a1.x + b1.x; s1.y = a1.y + b1.y; s1.z = a1.z + b1.z; s1.w = a1.w + b1.w;
  return pack8(s0, s1);
}
__device__ __forceinline__ u8 f2fp8(float v) {
  const u32 t = __builtin_amdgcn_cvt_pk_fp8_f32(v, 0.f, 0u, false);
  return (u8)(t & 0xffu);
}
__device__ __forceinline__ void gload16(const void* g, void* l) {
  __builtin_amdgcn_global_load_lds(
      (const __attribute__((address_space(1))) void*)g,
      (__attribute__((address_space(3))) void*)l, 16, 0, 0);
}

// ---------------------------------------------------------------------------
// All 5 weight transposes in one launch. bn-blocks: [0,8)=val [8,16)=samp
// [16,20)=attn(->rows 256..383 of samp-attn buffer) [20,28)=dout [28,36)=out
// ---------------------------------------------------------------------------
__global__ __launch_bounds__(256) void k_cvt_w_all(
    const float* __restrict__ w_val, const float* __restrict__ w_samp,
    const float* __restrict__ w_attn, const float* __restrict__ w_dout,
    const float* __restrict__ w_out, u16* __restrict__ t_val,
    u16* __restrict__ t_sa, u16* __restrict__ t_dout, u16* __restrict__ t_out) {
  __shared__ float t[32][33];
  const int bn = blockIdx.x;
  const int bk = blockIdx.y;
  const int tid = threadIdx.x;
  const float* W; u16* Wt; int N, lb;
  if (bn < 8)       { W = w_val;  Wt = t_val;            N = 256; lb = bn; }
  else if (bn < 16) { W = w_samp; Wt = t_sa;             N = 256; lb = bn - 8; }
  else if (bn < 20) { W = w_attn; Wt = t_sa + 256 * 256; N = 128; lb = bn - 16; }
  else if (bn < 28) { W = w_dout; Wt = t_dout;           N = 256; lb = bn - 20; }
  else              { W = w_out;  Wt = t_out;            N = 256; lb = bn - 28; }
#pragma unroll
  for (int e = 0; e < 4; ++e) {
    const int i = e * 256 + tid;
    const int kk = i >> 5, nn = i & 31;
    t[kk][nn] = W[(bk * 32 + kk) * N + lb * 32 + nn];
  }
  __syncthreads();
#pragma unroll
  for (int e = 0; e < 4; ++e) {
    const int i = e * 256 + tid;
    const int nn = i >> 5, kk = i & 31;
    Wt[(lb * 32 + nn) * 256 + bk * 32 + kk] = f2b(t[kk][nn]);
  }
}

// ---------------------------------------------------------------------------
// MFMA GEMM, depth-1 register-prefetch pipeline:
// out[M][Ntot] = A_bf16[M][256] @ Wt_bf16[Ntot][256]^T + bias (+ addend f32).
// Tile 128x128xK64, 4 waves, XOR-swizzled LDS. Split bias, per-row bias scale.
// ---------------------------------------------------------------------------
template <bool OUT_BF16, bool HAS_ADD>
__global__ __launch_bounds__(256) void k_mfma(const u16* __restrict__ A,
                                              const u16* __restrict__ Wt,
                                              const float* __restrict__ bias,
                                              const float* __restrict__ bias2,
                                              int nsplit,
                                              const float* __restrict__ bias_scale,
                                              const float* __restrict__ addend,
                                              void* __restrict__ outp,
                                              int M, int Ntot) {
  __shared__ u16 As[128 * 64];
  __shared__ u16 Bs[128 * 64];
  const int tid = threadIdx.x;
  const int m0 = blockIdx.x * 128;
  const int n0 = blockIdx.y * 128;
  const int wave = tid >> 6;
  const int lane = tid & 63;
  const int wr = wave >> 1;
  const int wc = wave & 1;
  const int lr = lane & 15;
  const int lg = lane >> 4;
  const int srow = tid >> 3;   // 0..31
  const int slot = tid & 7;

  const u16* aptr[4];
  const u16* bptr[4];
  int soff[4];
#pragma unroll
  for (int c = 0; c < 4; ++c) {
    const int rowA = c * 32 + srow;
    const int ra = min(m0 + rowA, M - 1);
    aptr[c] = A + (long long)ra * 256 + slot * 8;
    bptr[c] = Wt + (long long)(n0 + rowA) * 256 + slot * 8;
    soff[c] = rowA * 64 + ((slot ^ (rowA & 7)) << 3);
  }

  f32x4 acc[4][4] = {};

  bf16x8 ca[4], cb[4];
#pragma unroll
  for (int c = 0; c < 4; ++c) {
    ca[c] = *reinterpret_cast<const bf16x8*>(aptr[c]);
    cb[c] = *reinterpret_cast<const bf16x8*>(bptr[c]);
  }

#pragma unroll
  for (int kt = 0; kt < 4; ++kt) {
    bf16x8 na[4], nb[4];
    if (kt < 3) {
      const int k1 = (kt + 1) * 64;
#pragma unroll
      for (int c = 0; c < 4; ++c) {
        na[c] = *reinterpret_cast<const bf16x8*>(aptr[c] + k1);
        nb[c] = *reinterpret_cast<const bf16x8*>(bptr[c] + k1);
      }
    }
#pragma unroll
    for (int c = 0; c < 4; ++c) {
      *reinterpret_cast<bf16x8*>(&As[soff[c]]) = ca[c];
      *reinterpret_cast<bf16x8*>(&Bs[soff[c]]) = cb[c];
    }
    __syncthreads();
#pragma unroll
    for (int ks = 0; ks < 2; ++ks) {
      bf16x8 af[4], bfr[4];
#pragma unroll
      for (int mi = 0; mi < 4; ++mi) {
        const int r = wr * 64 + mi * 16 + lr;
        const int s = ks * 4 + lg;
        af[mi] = *reinterpret_cast<const bf16x8*>(&As[r * 64 + ((s ^ (r & 7)) << 3)]);
      }
#pragma unroll
      for (int ni = 0; ni < 4; ++ni) {
        const int r = wc * 64 + ni * 16 + lr;
        const int s = ks * 4 + lg;
        bfr[ni] = *reinterpret_cast<const bf16x8*>(&Bs[r * 64 + ((s ^ (r & 7)) << 3)]);
      }
#pragma unroll
      for (int mi = 0; mi < 4; ++mi)
#pragma unroll
        for (int ni = 0; ni < 4; ++ni)
          acc[mi][ni] = __builtin_amdgcn_mfma_f32_16x16x32_bf16(af[mi], bfr[ni],
                                                                acc[mi][ni], 0, 0, 0);
    }
    if (kt < 3) {
      __syncthreads();
#pragma unroll
      for (int c = 0; c < 4; ++c) { ca[c] = na[c]; cb[c] = nb[c]; }
    }
  }

#pragma unroll
  for (int mi = 0; mi < 4; ++mi) {
#pragma unroll
    for (int reg = 0; reg < 4; ++reg) {
      const int row = m0 + wr * 64 + mi * 16 + lg * 4 + reg;
      if (row < M) {
        const float bs = bias_scale ? bias_scale[row] : 1.f;
#pragma unroll
        for (int ni = 0; ni < 4; ++ni) {
          const int col = n0 + wc * 64 + ni * 16 + lr;
          const float b = (bias2 && col >= nsplit) ? bias2[col - nsplit] : bias[col];
          float v = acc[mi][ni][reg] + b * bs;
          if (HAS_ADD) v += addend[(long long)row * Ntot + col];
          if (OUT_BF16)
            ((u16*)outp)[(long long)row * Ntot + col] = f2b(v);
          else
            ((float*)outp)[(long long)row * Ntot + col] = v;
        }
      }
    }
  }
}

// ---------------------------------------------------------------------------
// offaw GEMM with fused (query + query_pos) -> bf16 A staging.
// out[kNQ][384] f32; cols >= 256 take bias2 (attn logits).
// ---------------------------------------------------------------------------
__global__ __launch_bounds__(256) void k_mfma_qp(const float* __restrict__ q,
                                                 const float* __restrict__ qp,
                                                 const u16* __restrict__ Wt,
                                                 const float* __restrict__ bias,
                                                 const float* __restrict__ bias2,
                                                 float* __restrict__ outp) {
  constexpr int M = kNQ;
  constexpr int Ntot = 384;
  __shared__ u16 As[128 * 64];
  __shared__ u16 Bs[128 * 64];
  const int tid = threadIdx.x;
  const int m0 = blockIdx.x * 128;
  const int n0 = blockIdx.y * 128;
  const int wave = tid >> 6;
  const int lane = tid & 63;
  const int wr = wave >> 1;
  const int wc = wave & 1;
  const int lr = lane & 15;
  const int lg = lane >> 4;
  const int srow = tid >> 3;
  const int slot = tid & 7;

  const float* qptr[4];
  const float* pptr[4];
  const u16* bptr[4];
  int soff[4];
#pragma unroll
  for (int c = 0; c < 4; ++c) {
    const int rowA = c * 32 + srow;
    const int ra = min(m0 + rowA, M - 1);
    qptr[c] = q + (long long)ra * 256 + slot * 8;
    pptr[c] = qp + (long long)ra * 256 + slot * 8;
    bptr[c] = Wt + (long long)(n0 + rowA) * 256 + slot * 8;
    soff[c] = rowA * 64 + ((slot ^ (rowA & 7)) << 3);
  }

  f32x4 acc[4][4] = {};

  bf16x8 ca[4], cb[4];
#pragma unroll
  for (int c = 0; c < 4; ++c) {
    ca[c] = load8sum(qptr[c], pptr[c]);
    cb[c] = *reinterpret_cast<const bf16x8*>(bptr[c]);
  }

#pragma unroll
  for (int kt = 0; kt < 4; ++kt) {
    bf16x8 na[4], nb[4];
    if (kt < 3) {
      const int k1 = (kt + 1) * 64;
#pragma unroll
      for (int c = 0; c < 4; ++c) {
        na[c] = load8sum(qptr[c] + k1, pptr[c] + k1);
        nb[c] = *reinterpret_cast<const bf16x8*>(bptr[c] + k1);
      }
    }
#pragma unroll
    for (int c = 0; c < 4; ++c) {
      *reinterpret_cast<bf16x8*>(&As[soff[c]]) = ca[c];
      *reinterpret_cast<bf16x8*>(&Bs[soff[c]]) = cb[c];
    }
    __syncthreads();
#pragma unroll
    for (int ks = 0; ks < 2; ++ks) {
      bf16x8 af[4], bfr[4];
#pragma unroll
      for (int mi = 0; mi < 4; ++mi) {
        const int r = wr * 64 + mi * 16 + lr;
        const int s = ks * 4 + lg;
        af[mi] = *reinterpret_cast<const bf16x8*>(&As[r * 64 + ((s ^ (r & 7)) << 3)]);
      }
#pragma unroll
      for (int ni = 0; ni < 4; ++ni) {
        const int r = wc * 64 + ni * 16 + lr;
        const int s = ks * 4 + lg;
        bfr[ni] = *reinterpret_cast<const bf16x8*>(&Bs[r * 64 + ((s ^ (r & 7)) << 3)]);
      }
#pragma unroll
      for (int mi = 0; mi < 4; ++mi)
#pragma unroll
        for (int ni = 0; ni < 4; ++ni)
          acc[mi][ni] = __builtin_amdgcn_mfma_f32_16x16x32_bf16(af[mi], bfr[ni],
                                                                acc[mi][ni], 0, 0, 0);
    }
    if (kt < 3) {
      __syncthreads();
#pragma unroll
      for (int c = 0; c < 4; ++c) { ca[c] = na[c]; cb[c] = nb[c]; }
    }
  }

#pragma unroll
  for (int mi = 0; mi < 4; ++mi) {
#pragma unroll
    for (int reg = 0; reg < 4; ++reg) {
      const int row = m0 + wr * 64 + mi * 16 + lg * 4 + reg;
      if (row < M) {
#pragma unroll
        for (int ni = 0; ni < 4; ++ni) {
          const int col = n0 + wc * 64 + ni * 16 + lr;
          const float b = (col >= 256) ? bias2[col - 256] : bias[col];
          outp[(long long)row * Ntot + col] = acc[mi][ni][reg] + b;
        }
      }
    }
  }
}

// ---------------------------------------------------------------------------
// Value-projection GEMM, persistent memory-order, 2 blocks/CU (R15 proven).
// ---------------------------------------------------------------------------
__global__ __launch_bounds__(256, 2) void k_mfma_vproj(
    const float* __restrict__ value, const u16* __restrict__ Wt,
    const float* __restrict__ bias, u8* __restrict__ outp) {
  constexpr int M = kNK * kCams;   // 81600
  constexpr int NT = M / 16;       // 5100 tiles of 16 rows
  __shared__ u16 S[2][8192];       // 2 x 16 KB A double-buffer
  const int tid = threadIdx.x;
  const int w = tid >> 6;
  const int lane = tid & 63;
  const int lr = lane & 15;
  const int lg = lane >> 4;

  bf16x8 breg[4][8];
#pragma unroll
  for (int ni = 0; ni < 4; ++ni) {
    const int rb = w * 64 + ni * 16 + lr;
#pragma unroll
    for (int ks = 0; ks < 8; ++ks)
      breg[ni][ks] = *reinterpret_cast<const bf16x8*>(
          Wt + rb * 256 + ks * 32 + lg * 8);
  }
  float bcol[4];
#pragma unroll
  for (int ni = 0; ni < 4; ++ni) bcol[ni] = bias[w * 64 + ni * 16 + lr];

  int tg = blockIdx.x;
  {
#pragma unroll
    for (int i = 0; i < 4; ++i) {
      const int r = w * 4 + i;
      const int swz = ((r & 7) << 1) | (r >> 3);
      gload16(value + (long long)(tg * 16 + r) * 256 + ((lane ^ swz) << 2),
              (char*)&S[0][0] + r * 1024 + lane * 16);
    }
  }
  __syncthreads();

  int buf = 0;
  for (; tg < NT; tg += 512) {
    const int tn = tg + 512;
    if (tn < NT) {
#pragma unroll
      for (int i = 0; i < 4; ++i) {
        const int r = w * 4 + i;
        const int swz = ((r & 7) << 1) | (r >> 3);
        gload16(value + (long long)(tn * 16 + r) * 256 + ((lane ^ swz) << 2),
                (char*)&S[buf ^ 1][0] + r * 1024 + lane * 16);
      }
    }

    const float* Ab = (const float*)((const char*)&S[buf][0] + lr * 1024);
    const int swzr = ((lr & 7) << 1) | (lr >> 3);
    f32x4 acc[4] = {};
#pragma unroll
    for (int ks = 0; ks < 8; ++ks) {
      const int c0 = (ks * 8 + lg * 2) ^ swzr;
      const int c1 = (ks * 8 + lg * 2 + 1) ^ swzr;
      const f32x4 lo = *reinterpret_cast<const f32x4*>(Ab + c0 * 4);
      const f32x4 hi = *reinterpret_cast<const f32x4*>(Ab + c1 * 4);
      const bf16x8 af = cvt8(lo, hi);
#pragma unroll
      for (int ni = 0; ni < 4; ++ni)
        acc[ni] = __builtin_amdgcn_mfma_f32_16x16x32_bf16(af, breg[ni][ks],
                                                          acc[ni], 0, 0, 0);
    }

#pragma unroll
    for (int reg = 0; reg < 4; ++reg) {
      const u32 g = (u32)(tg * 16 + lg * 4 + reg);
      const u32 n = g / 6u;
      const u32 cam = g - n * 6u;
      u8* op = outp + ((long long)(cam * kNK + n)) * 256 + w * 64 + lr;
#pragma unroll
      for (int ni = 0; ni < 4; ++ni)
        op[ni * 16] = f2fp8(acc[ni][reg] + bcol[ni]);
    }

    __syncthreads();
    buf ^= 1;
  }
}

// ---------------------------------------------------------------------------
// Softmax over each 16-wide group; logits live at offaw[nq*384 + 256 + t].
// ---------------------------------------------------------------------------
__global__ __launch_bounds__(128) void k_softmax16(float* __restrict__ offaw) {
  const int nq = blockIdx.x;
  const int t = threadIdx.x;
  float* p = offaw + (long long)nq * 384 + 256 + t;
  float v = *p;
  float mx = v;
#pragma unroll
  for (int s = 1; s < 16; s <<= 1) mx = fmaxf(mx, __shfl_xor(mx, s));
  const float e = expf(v - mx);
  float sm = e;
#pragma unroll
  for (int s = 1; s < 16; s <<= 1) sm += __shfl_xor(sm, s);
  *p = e / sm;
}

// ---------------------------------------------------------------------------
// Camera projection of reference points + visibility mask.
// ---------------------------------------------------------------------------
__global__ __launch_bounds__(256) void k_proj_ref(const float* __restrict__ refpts,
                                                  const float* __restrict__ l2i,
                                                  const float* __restrict__ img_shape,
                                                  float* __restrict__ refcam,
                                                  float* __restrict__ valid) {
  const int idx = blockIdx.x * blockDim.x + threadIdx.x;
  if (idx >= kCams * kNQ) return;
  const int cam = idx / kNQ;
  const int nq = idx - cam * kNQ;
  const float* Mp = l2i + cam * 12;
  float m[12];
#pragma unroll
  for (int i = 0; i < 12; ++i) m[i] = Mp[i];
  const float ih = img_shape[cam * 2 + 0];
  const float iw = img_shape[cam * 2 + 1];
  float anyv = 0.f;
  float* rcout = refcam + (long long)idx * 8;
#pragma unroll
  for (int r = 0; r < 4; ++r) {
    const float* rp = refpts + ((long long)nq * 4 + r) * 3;
    const float X = rp[0] * 102.4f + (-51.2f);
    const float Y = rp[1] * 102.4f + (-51.2f);
    const float Z = rp[2] * 8.0f + (-5.0f);
    const float cx = m[0] * X + m[1] * Y + m[2] * Z + m[3];
    const float cy = m[4] * X + m[5] * Y + m[6] * Z + m[7];
    const float cz = m[8] * X + m[9] * Y + m[10] * Z + m[11];
    const float zc = fmaxf(cz, kEps);
    const float xn = cx / zc / iw;
    const float yn = cy / zc / ih;
    rcout[r * 2 + 0] = xn;
    rcout[r * 2 + 1] = yn;
    if ((cz > kEps) && (xn > 0.f) && (xn < 1.f) && (yn > 0.f) && (yn < 1.f)) anyv = 1.f;
  }
  valid[idx] = anyv;
}

// ---------------------------------------------------------------------------
// Bilinear sampling with fused masked camera-mean; vproj is fp8-e4m3
// [cam][n][256]. One wave per query; block = 256 (4 queries) for better
// wave packing. lane = h*8 + d4 (4 ch). Level params hoisted (cam-invariant).
// ---------------------------------------------------------------------------
__global__ __launch_bounds__(256) void k_sample(const u8* __restrict__ vproj,
                                                const float* __restrict__ refcam,
                                                const float* __restrict__ offaw,
                                                const float* __restrict__ valid,
                                                u16* __restrict__ pre,
                                                float* __restrict__ cflag) {
  const int nq = blockIdx.x * 4 + (threadIdx.x >> 6);
  const int lane = threadIdx.x & 63;
  const int h = lane >> 3;
  const int d4 = lane & 7;

  static constexpr int SHH[4] = {64, 32, 16, 8};
  static constexpr int SHW[4] = {160, 80, 40, 20};
  static constexpr int LSI[4] = {0, 10240, 12800, 13440};

  const float* offp = offaw + (long long)nq * 384 + h * 32;
  const float* awp = offaw + (long long)nq * 384 + 256 + h * 16;

  // hoist camera-invariant per-level params (weights + offsets)
  float4 aw4s[4], ofAs[4], ofBs[4];
#pragma unroll
  for (int l = 0; l < 4; ++l) {
    aw4s[l] = *reinterpret_cast<const float4*>(awp + l * 4);
    ofAs[l] = *reinterpret_cast<const float4*>(offp + l * 8);
    ofBs[l] = *reinterpret_cast<const float4*>(offp + l * 8 + 4);
  }

  float vl[kCams];
#pragma unroll
  for (int c = 0; c < kCams; ++c) vl[c] = valid[c * kNQ + nq];

  float4 acc4 = {0.f, 0.f, 0.f, 0.f};
  float count = 0.f;

  for (int cam = 0; cam < kCams; ++cam) {
    if (vl[cam] == 0.f) continue;  // wave-uniform skip
    count += 1.f;

    const float* rcp = refcam + (long long)(cam * kNQ + nq) * 8;
    const float4 rcA = *reinterpret_cast<const float4*>(rcp);
    const float4 rcB = *reinterpret_cast<const float4*>(rcp + 4);
    const float rx[4] = {rcA.x, rcA.z, rcB.x, rcB.z};
    const float ry[4] = {rcA.y, rcA.w, rcB.y, rcB.w};

#pragma unroll
    for (int l = 0; l < 4; ++l) {
      const int Hl = SHH[l];
      const int Wl = SHW[l];
      const float Hf = (float)Hl;
      const float Wf = (float)Wl;
      const u8* vf = vproj + ((long long)(cam * kNK + LSI[l])) * 256 + h * 32 + d4 * 4;

      const float ox[4] = {ofAs[l].x, ofAs[l].z, ofBs[l].x, ofBs[l].z};
      const float oy[4] = {ofAs[l].y, ofAs[l].w, ofBs[l].y, ofBs[l].w};
      const float wr[4] = {aw4s[l].x, aw4s[l].y, aw4s[l].z, aw4s[l].w};

#pragma unroll
      for (int r = 0; r < 4; ++r) {
        const float x = fmaf(rx[r], Wf, ox[r]) - 0.5f;
        const float y = fmaf(ry[r], Hf, oy[r]) - 0.5f;
        const float x0 = floorf(x);
        const float y0 = floorf(y);
        const float lx = x - x0;
        const float ly = y - y0;
        const int ix = (int)x0;
        const int iy = (int)y0;
        const int ix0 = min(max(ix, 0), Wl - 1);
        const int ix1 = min(max(ix + 1, 0), Wl - 1);
        const int iy0 = min(max(iy, 0), Hl - 1);
        const int iy1 = min(max(iy + 1, 0), Hl - 1);
        const bool bx0 = (ix >= 0) & (ix < Wl);
        const bool bx1 = (ix >= -1) & (ix + 1 < Wl);
        const bool by0 = (iy >= 0) & (iy < Hl);
        const bool by1 = (iy >= -1) & (iy + 1 < Hl);
        const float w = wr[r];
        const float wy0 = w * (1.f - ly);
        const float wy1 = w * ly;
        const float w00 = (by0 && bx0) ? wy0 * (1.f - lx) : 0.f;
        const float w01 = (by0 && bx1) ? wy0 * lx : 0.f;
        const float w10 = (by1 && bx0) ? wy1 * (1.f - lx) : 0.f;
        const float w11 = (by1 && bx1) ? wy1 * lx : 0.f;
        const int q00 = *reinterpret_cast<const u32*>(vf + (iy0 * Wl + ix0) * 256);
        const int q01 = *reinterpret_cast<const u32*>(vf + (iy0 * Wl + ix1) * 256);
        const int q10 = *reinterpret_cast<const u32*>(vf + (iy1 * Wl + ix0) * 256);
        const int q11 = *reinterpret_cast<const u32*>(vf + (iy1 * Wl + ix1) * 256);
        const f32x2 a00 = __builtin_amdgcn_cvt_pk_f32_fp8(q00, false);
        const f32x2 b00 = __builtin_amdgcn_cvt_pk_f32_fp8(q00, true);
        const f32x2 a01 = __builtin_amdgcn_cvt_pk_f32_fp8(q01, false);
        const f32x2 b01 = __builtin_amdgcn_cvt_pk_f32_fp8(q01, true);
        const f32x2 a10 = __builtin_amdgcn_cvt_pk_f32_fp8(q10, false);
        const f32x2 b10 = __builtin_amdgcn_cvt_pk_f32_fp8(q10, true);
        const f32x2 a11 = __builtin_amdgcn_cvt_pk_f32_fp8(q11, false);
        const f32x2 b11 = __builtin_amdgcn_cvt_pk_f32_fp8(q11, true);
        acc4.x = fmaf(w00, a00[0], fmaf(w01, a01[0], fmaf(w10, a10[0], fmaf(w11, a11[0], acc4.x))));
        acc4.y = fmaf(w00, a00[1], fmaf(w01, a01[1], fmaf(w10, a10[1], fmaf(w11, a11[1], acc4.y))));
        acc4.z = fmaf(w00, b00[0], fmaf(w01, b01[0], fmaf(w10, b10[0], fmaf(w11, b11[0], acc4.z))));
        acc4.w = fmaf(w00, b00[1], fmaf(w01, b01[1], fmaf(w10, b10[1], fmaf(w11, b11[1], acc4.w))));
      }
    }
  }

  const float inv = count > 0.f ? (1.f / count) : 0.f;
  ushort4 o;
  o.x = f2b(acc4.x * inv);
  o.y = f2b(acc4.y * inv);
  o.z = f2b(acc4.z * inv);
  o.w = f2b(acc4.w * inv);
  *reinterpret_cast<ushort4*>(pre + (long long)nq * kC + h * 32 + d4 * 4) = o;
  if (lane == 0) cflag[nq] = count > 0.f ? 1.f : 0.f;
}

}  // namespace

extern "C" void kernel_launch(void* const* d_in, const int* in_sizes, int n_in,
                              void* d_out, int out_size, void* d_ws, size_t ws_size,
                              hipStream_t stream) {
  (void)in_sizes; (void)n_in; (void)out_size; (void)ws_size;
  const float* query     = (const float*)d_in[0];
  const float* query_pos = (const float*)d_in[1];
  const float* value     = (const float*)d_in[2];
  const float* refpts    = (const float*)d_in[3];
  const float* l2i       = (const float*)d_in[4];
  const float* img_shape = (const float*)d_in[5];
  const float* W_val  = (const float*)d_in[8];
  const float* b_val  = (const float*)d_in[9];
  const float* W_samp = (const float*)d_in[10];
  const float* b_samp = (const float*)d_in[11];
  const float* W_attn = (const float*)d_in[12];
  const float* b_attn = (const float*)d_in[13];
  const float* W_dout = (const float*)d_in[14];
  const float* b_dout = (const float*)d_in[15];
  const float* W_out  = (const float*)d_in[16];
  const float* b_out  = (const float*)d_in[17];

  // workspace layout (bytes, 16B-aligned)
  char* p = (char*)d_ws;
  float* offaw  = (float*)p;  p += 15360000;   // [10000][384] f32 (off | aw)
  float* refcam = (float*)p;  p += 1920000;    // [6*10000][8] f32
  float* valid  = (float*)p;  p += 240000;     // [6*10000] f32
  float* cflag  = (float*)p;  p += 40000;      // [10000] f32
  u8*    vproj  = (u8*)p;     p += 20889600;   // [6*13600][256] fp8-e4m3
  u16*   pre    = (u16*)p;    p += 5120000;    // [10000][256] bf16
  u16*   slots  = (u16*)p;    p += 5120000;    // [10000][256] bf16
  u16*   WtVal  = (u16*)p;    p += 131072;     // [256][256] bf16
  u16*   WtSA   = (u16*)p;    p += 196608;     // [384][256] bf16 (samp|attn)
  u16*   WtDout = (u16*)p;    p += 131072;
  u16*   WtOut  = (u16*)p;    p += 131072;
  float* out    = (float*)d_out;

  // weight transposes (1 launch)
  k_cvt_w_all<<<dim3(36, 8), 256, 0, stream>>>(W_val, W_samp, W_attn, W_dout, W_out,
                                               WtVal, WtSA, WtDout, WtOut);

  // camera projection + visibility
  k_proj_ref<<<dim3((kCams * kNQ + 255) / 256), 256, 0, stream>>>(refpts, l2i,
                                                                  img_shape, refcam,
                                                                  valid);

  // combined sampling-offset + attention-logit projection with fused
  // (q + q_pos) bf16 staging -> offaw [10000][384]
  k_mfma_qp<<<dim3(79, 3), 256, 0, stream>>>(query, query_pos, WtSA, b_samp,
                                             b_attn, offaw);
  k_softmax16<<<dim3(kNQ), 128, 0, stream>>>(offaw);

  // value projection (persistent memory-order, B-in-regs, 2 blocks/CU) -> fp8
  k_mfma_vproj<<<dim3(512), 256, 0, stream>>>(value, WtVal, b_val, vproj);

  // bilinear sampling + fused masked camera-mean -> pre, cflag
  k_sample<<<dim3(kNQ / 4), 256, 0, stream>>>(vproj, refcam, offaw, valid, pre,
                                              cflag);

  // dout projection on camera-averaged features (bias scaled by cflag)
  k_mfma<true, false><<<dim3(79, 2), 256, 0, stream>>>(
      pre, WtDout, b_dout, nullptr, 0, cflag, nullptr, slots, kNQ, 256);

  // final projection + residual
  k_mfma<false, true><<<dim3(79, 2), 256, 0, stream>>>(
      slots, WtOut, b_out, nullptr, 0, nullptr, query, out, kNQ, 256);
}

// Round 17
// 119.998 us; speedup vs baseline: 1.0767x; 1.0767x over previous
//
#include <hip/hip_runtime.h>
#include <hip/hip_bf16.h>

namespace {

typedef unsigned short u16;
typedef unsigned int u32;
typedef unsigned char u8;
typedef __attribute__((ext_vector_type(8))) short bf16x8;
typedef __attribute__((ext_vector_type(4))) float f32x4;
typedef __attribute__((ext_vector_type(2))) float f32x2;

constexpr int kNQ   = 10000;
constexpr int kCams = 6;
constexpr int kC    = 256;
constexpr int kNK   = 13600;
constexpr float kEps = 1e-5f;

__device__ __forceinline__ u16 f2b(float f) {
  union { __hip_bfloat16 h; u16 u; } cv;
  cv.h = __float2bfloat16(f);   // hardware cvt, RNE
  return cv.u;
}
__device__ __forceinline__ float b2f(u16 b) {
  return __uint_as_float(((u32)b) << 16);
}
__device__ __forceinline__ bf16x8 pack8(const float4& a, const float4& b) {
  bf16x8 v;
  v[0] = (short)f2b(a.x); v[1] = (short)f2b(a.y);
  v[2] = (short)f2b(a.z); v[3] = (short)f2b(a.w);
  v[4] = (short)f2b(b.x); v[5] = (short)f2b(b.y);
  v[6] = (short)f2b(b.z); v[7] = (short)f2b(b.w);
  return v;
}
__device__ __forceinline__ bf16x8 cvt8(const f32x4 lo, const f32x4 hi) {
  bf16x8 v;
  v[0] = (short)f2b(lo[0]); v[1] = (short)f2b(lo[1]);
  v[2] = (short)f2b(lo[2]); v[3] = (short)f2b(lo[3]);
  v[4] = (short)f2b(hi[0]); v[5] = (short)f2b(hi[1]);
  v[6] = (short)f2b(hi[2]); v[7] = (short)f2b(hi[3]);
  return v;
}
__device__ __forceinline__ u8 f2fp8(float v) {
  const u32 t = __builtin_amdgcn_cvt_pk_fp8_f32(v, 0.f, 0u, false);
  return (u8)(t & 0xffu);
}
__device__ __forceinline__ void gload16(const void* g, void* l) {
  __builtin_amdgcn_global_load_lds(
      (const __attribute__((address_space(1))) void*)g,
      (__attribute__((address_space(3))) void*)l, 16, 0, 0);
}

// ---------------------------------------------------------------------------
// All 5 weight transposes in one launch. bn-blocks: [0,8)=val [8,16)=samp
// [16,20)=attn(->rows 256..383 of samp-attn buffer) [20,28)=dout [28,36)=out
// ---------------------------------------------------------------------------
__global__ __launch_bounds__(256) void k_cvt_w_all(
    const float* __restrict__ w_val, const float* __restrict__ w_samp,
    const float* __restrict__ w_attn, const float* __restrict__ w_dout,
    const float* __restrict__ w_out, u16* __restrict__ t_val,
    u16* __restrict__ t_sa, u16* __restrict__ t_dout, u16* __restrict__ t_out) {
  __shared__ float t[32][33];
  const int bn = blockIdx.x;
  const int bk = blockIdx.y;
  const int tid = threadIdx.x;
  const float* W; u16* Wt; int N, lb;
  if (bn < 8)       { W = w_val;  Wt = t_val;            N = 256; lb = bn; }
  else if (bn < 16) { W = w_samp; Wt = t_sa;             N = 256; lb = bn - 8; }
  else if (bn < 20) { W = w_attn; Wt = t_sa + 256 * 256; N = 128; lb = bn - 16; }
  else if (bn < 28) { W = w_dout; Wt = t_dout;           N = 256; lb = bn - 20; }
  else              { W = w_out;  Wt = t_out;            N = 256; lb = bn - 28; }
#pragma unroll
  for (int e = 0; e < 4; ++e) {
    const int i = e * 256 + tid;
    const int kk = i >> 5, nn = i & 31;
    t[kk][nn] = W[(bk * 32 + kk) * N + lb * 32 + nn];
  }
  __syncthreads();
#pragma unroll
  for (int e = 0; e < 4; ++e) {
    const int i = e * 256 + tid;
    const int nn = i >> 5, kk = i & 31;
    Wt[(lb * 32 + nn) * 256 + bk * 32 + kk] = f2b(t[kk][nn]);
  }
}

// ---------------------------------------------------------------------------
// qpq[i] = bf16(a[i] + b[i]); 8 elems/thread
// ---------------------------------------------------------------------------
__global__ __launch_bounds__(256) void k_cvt_add(const float* __restrict__ a,
                                                 const float* __restrict__ b,
                                                 u16* __restrict__ out) {
  const int t = blockIdx.x * 256 + threadIdx.x;
  const int i = t * 8;
  const float4 x0 = *reinterpret_cast<const float4*>(a + i);
  const float4 x1 = *reinterpret_cast<const float4*>(a + i + 4);
  const float4 y0 = *reinterpret_cast<const float4*>(b + i);
  const float4 y1 = *reinterpret_cast<const float4*>(b + i + 4);
  float4 s0, s1;
  s0.x = x0.x + y0.x; s0.y = x0.y + y0.y; s0.z = x0.z + y0.z; s0.w = x0.w + y0.w;
  s1.x = x1.x + y1.x; s1.y = x1.y + y1.y; s1.z = x1.z + y1.z; s1.w = x1.w + y1.w;
  *reinterpret_cast<bf16x8*>(out + i) = pack8(s0, s1);
}

// ---------------------------------------------------------------------------
// MFMA GEMM, depth-1 register-prefetch pipeline:
// out[M][Ntot] = A_bf16[M][256] @ Wt_bf16[Ntot][256]^T + bias (+ addend f32).
// Tile 128x128xK64, 4 waves, XOR-swizzled LDS. Split bias, per-row bias scale.
// ---------------------------------------------------------------------------
template <bool OUT_BF16, bool HAS_ADD>
__global__ __launch_bounds__(256) void k_mfma(const u16* __restrict__ A,
                                              const u16* __restrict__ Wt,
                                              const float* __restrict__ bias,
                                              const float* __restrict__ bias2,
                                              int nsplit,
                                              const float* __restrict__ bias_scale,
                                              const float* __restrict__ addend,
                                              void* __restrict__ outp,
                                              int M, int Ntot) {
  __shared__ u16 As[128 * 64];
  __shared__ u16 Bs[128 * 64];
  const int tid = threadIdx.x;
  const int m0 = blockIdx.x * 128;
  const int n0 = blockIdx.y * 128;
  const int wave = tid >> 6;
  const int lane = tid & 63;
  const int wr = wave >> 1;
  const int wc = wave & 1;
  const int lr = lane & 15;
  const int lg = lane >> 4;
  const int srow = tid >> 3;   // 0..31
  const int slot = tid & 7;

  const u16* aptr[4];
  const u16* bptr[4];
  int soff[4];
#pragma unroll
  for (int c = 0; c < 4; ++c) {
    const int rowA = c * 32 + srow;
    const int ra = min(m0 + rowA, M - 1);
    aptr[c] = A + (long long)ra * 256 + slot * 8;
    bptr[c] = Wt + (long long)(n0 + rowA) * 256 + slot * 8;
    soff[c] = rowA * 64 + ((slot ^ (rowA & 7)) << 3);
  }

  f32x4 acc[4][4] = {};

  bf16x8 ca[4], cb[4];
#pragma unroll
  for (int c = 0; c < 4; ++c) {
    ca[c] = *reinterpret_cast<const bf16x8*>(aptr[c]);
    cb[c] = *reinterpret_cast<const bf16x8*>(bptr[c]);
  }

#pragma unroll
  for (int kt = 0; kt < 4; ++kt) {
    bf16x8 na[4], nb[4];
    if (kt < 3) {
      const int k1 = (kt + 1) * 64;
#pragma unroll
      for (int c = 0; c < 4; ++c) {
        na[c] = *reinterpret_cast<const bf16x8*>(aptr[c] + k1);
        nb[c] = *reinterpret_cast<const bf16x8*>(bptr[c] + k1);
      }
    }
#pragma unroll
    for (int c = 0; c < 4; ++c) {
      *reinterpret_cast<bf16x8*>(&As[soff[c]]) = ca[c];
      *reinterpret_cast<bf16x8*>(&Bs[soff[c]]) = cb[c];
    }
    __syncthreads();
#pragma unroll
    for (int ks = 0; ks < 2; ++ks) {
      bf16x8 af[4], bfr[4];
#pragma unroll
      for (int mi = 0; mi < 4; ++mi) {
        const int r = wr * 64 + mi * 16 + lr;
        const int s = ks * 4 + lg;
        af[mi] = *reinterpret_cast<const bf16x8*>(&As[r * 64 + ((s ^ (r & 7)) << 3)]);
      }
#pragma unroll
      for (int ni = 0; ni < 4; ++ni) {
        const int r = wc * 64 + ni * 16 + lr;
        const int s = ks * 4 + lg;
        bfr[ni] = *reinterpret_cast<const bf16x8*>(&Bs[r * 64 + ((s ^ (r & 7)) << 3)]);
      }
#pragma unroll
      for (int mi = 0; mi < 4; ++mi)
#pragma unroll
        for (int ni = 0; ni < 4; ++ni)
          acc[mi][ni] = __builtin_amdgcn_mfma_f32_16x16x32_bf16(af[mi], bfr[ni],
                                                                acc[mi][ni], 0, 0, 0);
    }
    if (kt < 3) {
      __syncthreads();
#pragma unroll
      for (int c = 0; c < 4; ++c) { ca[c] = na[c]; cb[c] = nb[c]; }
    }
  }

#pragma unroll
  for (int mi = 0; mi < 4; ++mi) {
#pragma unroll
    for (int reg = 0; reg < 4; ++reg) {
      const int row = m0 + wr * 64 + mi * 16 + lg * 4 + reg;
      if (row < M) {
        const float bs = bias_scale ? bias_scale[row] : 1.f;
#pragma unroll
        for (int ni = 0; ni < 4; ++ni) {
          const int col = n0 + wc * 64 + ni * 16 + lr;
          const float b = (bias2 && col >= nsplit) ? bias2[col - nsplit] : bias[col];
          float v = acc[mi][ni][reg] + b * bs;
          if (HAS_ADD) v += addend[(long long)row * Ntot + col];
          if (OUT_BF16)
            ((u16*)outp)[(long long)row * Ntot + col] = f2b(v);
          else
            ((float*)outp)[(long long)row * Ntot + col] = v;
        }
      }
    }
  }
}

// ---------------------------------------------------------------------------
// Value-projection GEMM, persistent memory-order, 2 blocks/CU (R15 proven):
// grid=512 x 256 thr (4 waves). B panel (64 cols x K=256) loaded DIRECTLY
// from global Wt into 128 VGPRs per wave; LDS is only the 2x16 KB A dbuf.
// A read in MEMORY order (16 contiguous rows x 1 KB via gload_lds).
// Epilogue: scattered fp8 store (memory row n*6+cam -> vproj[cam][n]).
// ---------------------------------------------------------------------------
__global__ __launch_bounds__(256, 2) void k_mfma_vproj(
    const float* __restrict__ value, const u16* __restrict__ Wt,
    const float* __restrict__ bias, u8* __restrict__ outp) {
  constexpr int M = kNK * kCams;   // 81600
  constexpr int NT = M / 16;       // 5100 tiles of 16 rows
  __shared__ u16 S[2][8192];       // 2 x 16 KB A double-buffer
  const int tid = threadIdx.x;
  const int w = tid >> 6;          // 0..3
  const int lane = tid & 63;
  const int lr = lane & 15;
  const int lg = lane >> 4;

  bf16x8 breg[4][8];   // [ni][ks] -> 128 VGPR
#pragma unroll
  for (int ni = 0; ni < 4; ++ni) {
    const int rb = w * 64 + ni * 16 + lr;
#pragma unroll
    for (int ks = 0; ks < 8; ++ks)
      breg[ni][ks] = *reinterpret_cast<const bf16x8*>(
          Wt + rb * 256 + ks * 32 + lg * 8);
  }
  float bcol[4];
#pragma unroll
  for (int ni = 0; ni < 4; ++ni) bcol[ni] = bias[w * 64 + ni * 16 + lr];

  int tg = blockIdx.x;
  {
#pragma unroll
    for (int i = 0; i < 4; ++i) {
      const int r = w * 4 + i;
      const int swz = ((r & 7) << 1) | (r >> 3);
      gload16(value + (long long)(tg * 16 + r) * 256 + ((lane ^ swz) << 2),
              (char*)&S[0][0] + r * 1024 + lane * 16);
    }
  }
  __syncthreads();   // A(t0) resident in buf0

  int buf = 0;
  for (; tg < NT; tg += 512) {
    const int tn = tg + 512;
    if (tn < NT) {
#pragma unroll
      for (int i = 0; i < 4; ++i) {
        const int r = w * 4 + i;
        const int swz = ((r & 7) << 1) | (r >> 3);
        gload16(value + (long long)(tn * 16 + r) * 256 + ((lane ^ swz) << 2),
                (char*)&S[buf ^ 1][0] + r * 1024 + lane * 16);
      }
    }

    const float* Ab = (const float*)((const char*)&S[buf][0] + lr * 1024);
    const int swzr = ((lr & 7) << 1) | (lr >> 3);
    f32x4 acc[4] = {};
#pragma unroll
    for (int ks = 0; ks < 8; ++ks) {
      const int c0 = (ks * 8 + lg * 2) ^ swzr;
      const int c1 = (ks * 8 + lg * 2 + 1) ^ swzr;
      const f32x4 lo = *reinterpret_cast<const f32x4*>(Ab + c0 * 4);
      const f32x4 hi = *reinterpret_cast<const f32x4*>(Ab + c1 * 4);
      const bf16x8 af = cvt8(lo, hi);
#pragma unroll
      for (int ni = 0; ni < 4; ++ni)
        acc[ni] = __builtin_amdgcn_mfma_f32_16x16x32_bf16(af, breg[ni][ks],
                                                          acc[ni], 0, 0, 0);
    }

#pragma unroll
    for (int reg = 0; reg < 4; ++reg) {
      const u32 g = (u32)(tg * 16 + lg * 4 + reg);
      const u32 n = g / 6u;
      const u32 cam = g - n * 6u;
      u8* op = outp + ((long long)(cam * kNK + n)) * 256 + w * 64 + lr;
#pragma unroll
      for (int ni = 0; ni < 4; ++ni)
        op[ni * 16] = f2fp8(acc[ni][reg] + bcol[ni]);
    }

    __syncthreads();
    buf ^= 1;
  }
}

// ---------------------------------------------------------------------------
// Softmax over each 16-wide group; logits live at offaw[nq*384 + 256 + t].
// ---------------------------------------------------------------------------
__global__ __launch_bounds__(128) void k_softmax16(float* __restrict__ offaw) {
  const int nq = blockIdx.x;
  const int t = threadIdx.x;
  float* p = offaw + (long long)nq * 384 + 256 + t;
  float v = *p;
  float mx = v;
#pragma unroll
  for (int s = 1; s < 16; s <<= 1) mx = fmaxf(mx, __shfl_xor(mx, s));
  const float e = expf(v - mx);
  float sm = e;
#pragma unroll
  for (int s = 1; s < 16; s <<= 1) sm += __shfl_xor(sm, s);
  *p = e / sm;
}

// ---------------------------------------------------------------------------
// Camera projection of reference points + visibility mask.
// ---------------------------------------------------------------------------
__global__ __launch_bounds__(256) void k_proj_ref(const float* __restrict__ refpts,
                                                  const float* __restrict__ l2i,
                                                  const float* __restrict__ img_shape,
                                                  float* __restrict__ refcam,
                                                  float* __restrict__ valid) {
  const int idx = blockIdx.x * blockDim.x + threadIdx.x;
  if (idx >= kCams * kNQ) return;
  const int cam = idx / kNQ;
  const int nq = idx - cam * kNQ;
  const float* Mp = l2i + cam * 12;
  float m[12];
#pragma unroll
  for (int i = 0; i < 12; ++i) m[i] = Mp[i];
  const float ih = img_shape[cam * 2 + 0];
  const float iw = img_shape[cam * 2 + 1];
  float anyv = 0.f;
  float* rcout = refcam + (long long)idx * 8;
#pragma unroll
  for (int r = 0; r < 4; ++r) {
    const float* rp = refpts + ((long long)nq * 4 + r) * 3;
    const float X = rp[0] * 102.4f + (-51.2f);
    const float Y = rp[1] * 102.4f + (-51.2f);
    const float Z = rp[2] * 8.0f + (-5.0f);
    const float cx = m[0] * X + m[1] * Y + m[2] * Z + m[3];
    const float cy = m[4] * X + m[5] * Y + m[6] * Z + m[7];
    const float cz = m[8] * X + m[9] * Y + m[10] * Z + m[11];
    const float zc = fmaxf(cz, kEps);
    const float xn = cx / zc / iw;
    const float yn = cy / zc / ih;
    rcout[r * 2 + 0] = xn;
    rcout[r * 2 + 1] = yn;
    if ((cz > kEps) && (xn > 0.f) && (xn < 1.f) && (yn > 0.f) && (yn < 1.f)) anyv = 1.f;
  }
  valid[idx] = anyv;
}

// ---------------------------------------------------------------------------
// Bilinear sampling with fused masked camera-mean; vproj is fp8-e4m3
// [cam][n][256]. One wave per query (block = 64); lane = h*8 + d4 (4 ch).
// Level params (aw/off) are camera-invariant: hoisted before the cam loop.
// ---------------------------------------------------------------------------
__global__ __launch_bounds__(64) void k_sample(const u8* __restrict__ vproj,
                                               const float* __restrict__ refcam,
                                               const float* __restrict__ offaw,
                                               const float* __restrict__ valid,
                                               u16* __restrict__ pre,
                                               float* __restrict__ cflag) {
  const int nq = blockIdx.x;
  const int lane = threadIdx.x;
  const int h = lane >> 3;
  const int d4 = lane & 7;

  static constexpr int SHH[4] = {64, 32, 16, 8};
  static constexpr int SHW[4] = {160, 80, 40, 20};
  static constexpr int LSI[4] = {0, 10240, 12800, 13440};

  const float* offp = offaw + (long long)nq * 384 + h * 32;
  const float* awp = offaw + (long long)nq * 384 + 256 + h * 16;

  // hoist camera-invariant per-level params (weights + offsets)
  float4 aw4s[4], ofAs[4], ofBs[4];
#pragma unroll
  for (int l = 0; l < 4; ++l) {
    aw4s[l] = *reinterpret_cast<const float4*>(awp + l * 4);
    ofAs[l] = *reinterpret_cast<const float4*>(offp + l * 8);
    ofBs[l] = *reinterpret_cast<const float4*>(offp + l * 8 + 4);
  }

  float vl[kCams];
#pragma unroll
  for (int c = 0; c < kCams; ++c) vl[c] = valid[c * kNQ + nq];

  float4 acc4 = {0.f, 0.f, 0.f, 0.f};
  float count = 0.f;

  for (int cam = 0; cam < kCams; ++cam) {
    if (vl[cam] == 0.f) continue;  // wave-uniform skip
    count += 1.f;

    const float* rcp = refcam + (long long)(cam * kNQ + nq) * 8;
    const float4 rcA = *reinterpret_cast<const float4*>(rcp);
    const float4 rcB = *reinterpret_cast<const float4*>(rcp + 4);
    const float rx[4] = {rcA.x, rcA.z, rcB.x, rcB.z};
    const float ry[4] = {rcA.y, rcA.w, rcB.y, rcB.w};

#pragma unroll
    for (int l = 0; l < 4; ++l) {
      const int Hl = SHH[l];
      const int Wl = SHW[l];
      const float Hf = (float)Hl;
      const float Wf = (float)Wl;
      const u8* vf = vproj + ((long long)(cam * kNK + LSI[l])) * 256 + h * 32 + d4 * 4;

      const float ox[4] = {ofAs[l].x, ofAs[l].z, ofBs[l].x, ofBs[l].z};
      const float oy[4] = {ofAs[l].y, ofAs[l].w, ofBs[l].y, ofBs[l].w};
      const float wr[4] = {aw4s[l].x, aw4s[l].y, aw4s[l].z, aw4s[l].w};

#pragma unroll
      for (int r = 0; r < 4; ++r) {
        const float x = fmaf(rx[r], Wf, ox[r]) - 0.5f;
        const float y = fmaf(ry[r], Hf, oy[r]) - 0.5f;
        const float x0 = floorf(x);
        const float y0 = floorf(y);
        const float lx = x - x0;
        const float ly = y - y0;
        const int ix = (int)x0;
        const int iy = (int)y0;
        const int ix0 = min(max(ix, 0), Wl - 1);
        const int ix1 = min(max(ix + 1, 0), Wl - 1);
        const int iy0 = min(max(iy, 0), Hl - 1);
        const int iy1 = min(max(iy + 1, 0), Hl - 1);
        const bool bx0 = (ix >= 0) & (ix < Wl);
        const bool bx1 = (ix >= -1) & (ix + 1 < Wl);
        const bool by0 = (iy >= 0) & (iy < Hl);
        const bool by1 = (iy >= -1) & (iy + 1 < Hl);
        const float w = wr[r];
        const float wy0 = w * (1.f - ly);
        const float wy1 = w * ly;
        const float w00 = (by0 && bx0) ? wy0 * (1.f - lx) : 0.f;
        const float w01 = (by0 && bx1) ? wy0 * lx : 0.f;
        const float w10 = (by1 && bx0) ? wy1 * (1.f - lx) : 0.f;
        const float w11 = (by1 && bx1) ? wy1 * lx : 0.f;
        const int q00 = *reinterpret_cast<const u32*>(vf + (iy0 * Wl + ix0) * 256);
        const int q01 = *reinterpret_cast<const u32*>(vf + (iy0 * Wl + ix1) * 256);
        const int q10 = *reinterpret_cast<const u32*>(vf + (iy1 * Wl + ix0) * 256);
        const int q11 = *reinterpret_cast<const u32*>(vf + (iy1 * Wl + ix1) * 256);
        const f32x2 a00 = __builtin_amdgcn_cvt_pk_f32_fp8(q00, false);
        const f32x2 b00 = __builtin_amdgcn_cvt_pk_f32_fp8(q00, true);
        const f32x2 a01 = __builtin_amdgcn_cvt_pk_f32_fp8(q01, false);
        const f32x2 b01 = __builtin_amdgcn_cvt_pk_f32_fp8(q01, true);
        const f32x2 a10 = __builtin_amdgcn_cvt_pk_f32_fp8(q10, false);
        const f32x2 b10 = __builtin_amdgcn_cvt_pk_f32_fp8(q10, true);
        const f32x2 a11 = __builtin_amdgcn_cvt_pk_f32_fp8(q11, false);
        const f32x2 b11 = __builtin_amdgcn_cvt_pk_f32_fp8(q11, true);
        acc4.x = fmaf(w00, a00[0], fmaf(w01, a01[0], fmaf(w10, a10[0], fmaf(w11, a11[0], acc4.x))));
        acc4.y = fmaf(w00, a00[1], fmaf(w01, a01[1], fmaf(w10, a10[1], fmaf(w11, a11[1], acc4.y))));
        acc4.z = fmaf(w00, b00[0], fmaf(w01, b01[0], fmaf(w10, b10[0], fmaf(w11, b11[0], acc4.z))));
        acc4.w = fmaf(w00, b00[1], fmaf(w01, b01[1], fmaf(w10, b10[1], fmaf(w11, b11[1], acc4.w))));
      }
    }
  }

  const float inv = count > 0.f ? (1.f / count) : 0.f;
  ushort4 o;
  o.x = f2b(acc4.x * inv);
  o.y = f2b(acc4.y * inv);
  o.z = f2b(acc4.z * inv);
  o.w = f2b(acc4.w * inv);
  *reinterpret_cast<ushort4*>(pre + (long long)nq * kC + h * 32 + d4 * 4) = o;
  if (lane == 0) cflag[nq] = count > 0.f ? 1.f : 0.f;
}

}  // namespace

extern "C" void kernel_launch(void* const* d_in, const int* in_sizes, int n_in,
                              void* d_out, int out_size, void* d_ws, size_t ws_size,
                              hipStream_t stream) {
  (void)in_sizes; (void)n_in; (void)out_size; (void)ws_size;
  const float* query     = (const float*)d_in[0];
  const float* query_pos = (const float*)d_in[1];
  const float* value     = (const float*)d_in[2];
  const float* refpts    = (const float*)d_in[3];
  const float* l2i       = (const float*)d_in[4];
  const float* img_shape = (const float*)d_in[5];
  const float* W_val  = (const float*)d_in[8];
  const float* b_val  = (const float*)d_in[9];
  const float* W_samp = (const float*)d_in[10];
  const float* b_samp = (const float*)d_in[11];
  const float* W_attn = (const float*)d_in[12];
  const float* b_attn = (const float*)d_in[13];
  const float* W_dout = (const float*)d_in[14];
  const float* b_dout = (const float*)d_in[15];
  const float* W_out  = (const float*)d_in[16];
  const float* b_out  = (const float*)d_in[17];

  // workspace layout (bytes, 16B-aligned)
  char* p = (char*)d_ws;
  float* offaw  = (float*)p;  p += 15360000;   // [10000][384] f32 (off | aw)
  float* refcam = (float*)p;  p += 1920000;    // [6*10000][8] f32
  float* valid  = (float*)p;  p += 240000;     // [6*10000] f32
  float* cflag  = (float*)p;  p += 40000;      // [10000] f32
  u8*    vproj  = (u8*)p;     p += 20889600;   // [6*13600][256] fp8-e4m3
  u16*   pre    = (u16*)p;    p += 5120000;    // [10000][256] bf16
  u16*   slots  = (u16*)p;    p += 5120000;    // [10000][256] bf16
  u16*   qpq    = (u16*)p;    p += 5120000;    // [10000][256] bf16
  u16*   WtVal  = (u16*)p;    p += 131072;     // [256][256] bf16
  u16*   WtSA   = (u16*)p;    p += 196608;     // [384][256] bf16 (samp|attn)
  u16*   WtDout = (u16*)p;    p += 131072;
  u16*   WtOut  = (u16*)p;    p += 131072;
  float* out    = (float*)d_out;

  // weight transposes (1 launch)
  k_cvt_w_all<<<dim3(36, 8), 256, 0, stream>>>(W_val, W_samp, W_attn, W_dout, W_out,
                                               WtVal, WtSA, WtDout, WtOut);

  // q + q_pos -> bf16
  k_cvt_add<<<dim3(1250), 256, 0, stream>>>(query, query_pos, qpq);

  // camera projection + visibility
  k_proj_ref<<<dim3((kCams * kNQ + 255) / 256), 256, 0, stream>>>(refpts, l2i,
                                                                  img_shape, refcam,
                                                                  valid);

  // combined sampling-offset + attention-logit projection -> offaw [10000][384]
  k_mfma<false, false><<<dim3(79, 3), 256, 0, stream>>>(
      qpq, WtSA, b_samp, b_attn, 256, nullptr, nullptr, offaw, kNQ, 384);
  k_softmax16<<<dim3(kNQ), 128, 0, stream>>>(offaw);

  // value projection (persistent memory-order, B-in-regs, 2 blocks/CU) -> fp8
  k_mfma_vproj<<<dim3(512), 256, 0, stream>>>(value, WtVal, b_val, vproj);

  // bilinear sampling + fused masked camera-mean -> pre, cflag
  k_sample<<<dim3(kNQ), 64, 0, stream>>>(vproj, refcam, offaw, valid, pre, cflag);

  // dout projection on camera-averaged features (bias scaled by cflag)
  k_mfma<true, false><<<dim3(79, 2), 256, 0, stream>>>(
      pre, WtDout, b_dout, nullptr, 0, cflag, nullptr, slots, kNQ, 256);

  // final projection + residual
  k_mfma<false, true><<<dim3(79, 2), 256, 0, stream>>>(
      slots, WtOut, b_out, nullptr, 0, nullptr, query, out, kNQ, 256);
}